// Round 10
// baseline (201.437 us; speedup 1.0000x reference)
//
#include <hip/hip_runtime.h>
#include <hip/hip_bf16.h>
#include <math.h>
#include <cstdint>

#define FEPS 1e-8f
#define NTHR 256
#define CAND_CAP 4096
#define NREP 32
#define H2BITS 17
#define H2SIZE (1u << H2BITS)
#define BAND 3e-3f          // screen band in z-space (>=300x the z~ error bound)
#define UCMP 1e-3f          // u-compare band (min |dg/du| = e -> |dg| > 2.7e-3 >> 2^-25)

#define GRID_MAP 2048
#define GRID_FIN 2048

// coarse sampled binning: 4096 bins over [-8, 24), width 1/128
#define ZMIN 8.0f
#define ZSCALE 128.0f
#define ZBINW 0.0078125f    // exact in f32

// ---------- numeric helpers ----------

// monotonic float <-> uint key mapping (order-preserving, ascending)
__device__ __forceinline__ uint32_t f2k(float f) {
    uint32_t b = __float_as_uint(f);
    return (b & 0x80000000u) ? ~b : (b | 0x80000000u);
}
__device__ __forceinline__ float k2f(uint32_t k) {
    uint32_t b = (k & 0x80000000u) ? (k & 0x7FFFFFFFu) : ~k;
    return __uint_as_float(b);
}

// exact-path gumbel: library logf (~1 ulp) — the "truth" z used for all counts
__device__ __forceinline__ float gum_fast(float u) {
    float t = u + FEPS;
    float a = logf(t);
    float w = -a + FEPS;
    return -logf(w);
}
// screen-path gumbel: fast __logf (few-ulp); |z~ - z| <= ~1e-5 << BAND
__device__ __forceinline__ float gum_scr(float u) {
    float t = u + FEPS;
    float a = __logf(t);
    float w = -a + FEPS;
    return -__logf(w);
}

// correctly-rounded-ish f32 log via f64 (refine/tie path; empirically matches np)
__device__ __forceinline__ float logCR(float x) { return (float)log((double)x); }
__device__ __forceinline__ float gum_cr(float u) {
    float t = u + FEPS;
    float a = logCR(t);
    float w = -a + FEPS;
    return -logCR(w);
}

// exact decision: out = 1 iff RN(v1 - v0) > 2^-25
__device__ __forceinline__ float decide_cr(float maskv, float ua, float ub) {
    float G0 = gum_cr(ua);
    float G1 = gum_cr(ub);
    float diff = (maskv + G1) - G0;
    return (diff > 0x1p-25f) ? 1.0f : 0.0f;
}

// ratio trick: out=1 iff w0 > exp(2^-25-mv)*w1; CR fallback in 1e-4 rel band
__device__ __forceinline__ float decide_fast(float mv, float ua, float ub) {
    float w0 = -__logf(ua + FEPS) + FEPS;
    float w1 = -__logf(ub + FEPS) + FEPS;
    float T = (mv != 0.0f) ? 0.36787944f : 1.0f;
    float rhs = T * w1;
    float q = w0 - rhs;
    if (fabsf(q) > 1e-4f * rhs) return (q > 0.0f) ? 1.0f : 0.0f;
    return decide_cr(mv, ua, ub);
}

// mask=0 decide: g1>g0 <=> ub>ua (log strictly monotone, same +eps both sides).
// |ub-ua| > 1e-3 => |g1-g0| >= e*1e-3 - fuzz >> 2^-25  -> pure compare.
__device__ __forceinline__ float decide0(float ua, float ub) {
    float d = ub - ua;
    if (fabsf(d) > UCMP) return (d > 0.0f) ? 1.0f : 0.0f;
    return decide_fast(0.0f, ua, ub);
}

__device__ __forceinline__ int zbin(float z) {
    float t = (z + ZMIN) * ZSCALE;
    int b = (int)t;
    if (b < 0) b = 0;
    if (b > 4095) b = 4095;
    return b;
}

// ---------- K0: zero workspace (~1 MB) ----------
__global__ void k_zero(uint32_t* __restrict__ hist1r, uint32_t* __restrict__ hist2,
                       uint32_t* __restrict__ scal, uint32_t* __restrict__ candCount) {
    int i = blockIdx.x * blockDim.x + threadIdx.x;
    int stride = gridDim.x * blockDim.x;
    for (int b = i; b < NREP * 4096; b += stride) hist1r[b] = 0u;
    for (uint32_t b = i; b < H2SIZE; b += stride) hist2[b] = 0u;
    if (i < 16) scal[i] = 0u;
    if (i == 0) *candCount = 0u;
}

// ---------- K1: SAMPLED coarse histogram (1/16 of elements, screen-z) ----------
__global__ void __launch_bounds__(NTHR) k_samp(
        const float* __restrict__ lg, const float* __restrict__ u1,
        const int* __restrict__ trainp, uint32_t* __restrict__ hist1r, int N) {
    __shared__ uint32_t h[4096];
    for (int b = threadIdx.x; b < 4096; b += NTHR) h[b] = 0u;
    __syncthreads();
    const int tr = *trainp;
    const int n4 = N >> 2;
    const int gtid = blockIdx.x * NTHR + threadIdx.x;    // 0..65535
    const float4* lg4 = (const float4*)lg;
    const float4* u14 = (const float4*)u1;
    #pragma unroll
    for (int q = 0; q < 4; q++) {
        int pos = (gtid + q * 65536) << 4;   // every 16th float4-position
        if (pos < n4) {
            float4 m = lg4[pos];
            float4 u = u14[pos];
            float z0 = tr ? m.x + gum_scr(u.x) : m.x;
            float z1 = tr ? m.y + gum_scr(u.y) : m.y;
            float z2 = tr ? m.z + gum_scr(u.z) : m.z;
            float z3 = tr ? m.w + gum_scr(u.w) : m.w;
            atomicAdd(&h[zbin(z0)], 1u); atomicAdd(&h[zbin(z1)], 1u);
            atomicAdd(&h[zbin(z2)], 1u); atomicAdd(&h[zbin(z3)], 1u);
        }
    }
    __syncthreads();
    uint32_t* rep = hist1r + (uint32_t)(blockIdx.x & (NREP - 1)) * 4096u;
    for (int b = threadIdx.x; b < 4096; b += NTHR) {
        uint32_t v = h[b];
        if (v) atomicAdd(&rep[b], v);
    }
}

// ---------- K2: scan sampled hist, pick coarse bin, emit keybase + screen cutoffs ----------
__global__ void __launch_bounds__(1024) k_scan1(
        const uint32_t* __restrict__ hist1r, const int* __restrict__ kptr,
        uint32_t* __restrict__ scal) {
    __shared__ uint32_t vals[4096];
    __shared__ uint32_t cnt[1024];
    const int t = threadIdx.x;
    uint32_t loc = 0;
    for (int j = 0; j < 4; j++) {
        const int bin = 4095 - (t * 4 + j);
        uint32_t v = 0;
        #pragma unroll
        for (int r = 0; r < NREP; r++) v += hist1r[r * 4096 + bin];
        vals[t * 4 + j] = v;
        loc += v;
    }
    cnt[t] = loc;
    __syncthreads();
    for (int off = 1; off < 1024; off <<= 1) {
        uint32_t add = (t >= off) ? cnt[t - off] : 0u;
        __syncthreads();
        cnt[t] += add;
        __syncthreads();
    }
    const float Kf = (float)(*kptr) * 0.0625f;   // target rank among 1/16 samples
    float excl = (t > 0) ? (float)cnt[t - 1] : 0.0f;
    float incl = (float)cnt[t];
    if (excl < Kf && Kf <= incl) {
        float c = excl;
        for (int j = 0; j < 4; j++) {
            float v = (float)vals[t * 4 + j];
            if (Kf <= c + v) {
                int b1 = 4095 - (t * 4 + j);          // estimated threshold bin
                int bmar = b1 - 2;                    // -2 bins ≈ -6 sigma sampling margin
                if (bmar < 0) bmar = 0;
                float elo = (float)bmar * ZBINW - ZMIN;  // exact dyadic edge
                uint32_t kb = f2k(elo);
                scal[0] = kb;
                float zlo = k2f(kb) - BAND;
                float zhi = k2f(kb + H2SIZE) + BAND;
                scal[6] = __float_as_uint(zlo);
                scal[7] = __float_as_uint(zhi);
                break;
            }
            c += v;
        }
    }
}

// ---------- K3: full sweep -> 2-bit class map + exact GT + 1-ulp hist2 ----------
// class 0: surely below range (mv=0); 1: surely above range (mv=1); 2: band (recompute later)
__global__ void __launch_bounds__(NTHR) k_map(
        const float* __restrict__ lg, const float* __restrict__ u1,
        const int* __restrict__ trainp, const uint32_t* __restrict__ scal_ro,
        uint32_t* __restrict__ hist2, uint32_t* __restrict__ scal,
        unsigned char* __restrict__ map, int N) {
    __shared__ uint32_t red[NTHR];
    const int tr = *trainp;
    const uint32_t kb = scal_ro[0];
    const uint32_t hiB = kb + H2SIZE;
    const float zlo_scr = __uint_as_float(scal_ro[6]);
    const float zhi_scr = __uint_as_float(scal_ro[7]);
    const int n4 = N >> 2;
    const int nth = gridDim.x * NTHR;
    const float4* lg4 = (const float4*)lg;
    const float4* u14 = (const float4*)u1;
    uint32_t gt = 0;

    int p0 = blockIdx.x * NTHR + threadIdx.x;
    while (p0 + nth < n4) {
        const int p1 = p0 + nth;
        float4 m0 = lg4[p0];
        float4 m1 = lg4[p1];
        float4 a0 = u14[p0];
        float4 a1 = u14[p1];
        float ms[8] = {m0.x, m0.y, m0.z, m0.w, m1.x, m1.y, m1.z, m1.w};
        float us[8] = {a0.x, a0.y, a0.z, a0.w, a1.x, a1.y, a1.z, a1.w};
        unsigned int bc0 = 0, bc1 = 0;
        #pragma unroll
        for (int j = 0; j < 8; j++) {
            float zh = tr ? ms[j] + gum_scr(us[j]) : ms[j];
            uint32_t cls;
            if (zh > zhi_scr) { cls = 1u; gt++; }
            else if (zh < zlo_scr) cls = 0u;
            else {
                float ze = tr ? ms[j] + gum_fast(us[j]) : ms[j];
                uint32_t key = f2k(ze);
                if (key >= hiB) { cls = 1u; gt++; }
                else if (key >= kb) { atomicAdd(&hist2[key - kb], 1u); cls = 2u; }
                else cls = 0u;
            }
            if (j < 4) bc0 |= cls << (2 * j);
            else bc1 |= cls << (2 * (j - 4));
        }
        map[p0] = (unsigned char)bc0;
        map[p1] = (unsigned char)bc1;
        p0 += 2 * nth;
    }
    if (p0 < n4) {
        float4 m0 = lg4[p0];
        float4 a0 = u14[p0];
        float ms[4] = {m0.x, m0.y, m0.z, m0.w};
        float us[4] = {a0.x, a0.y, a0.z, a0.w};
        unsigned int bc0 = 0;
        #pragma unroll
        for (int j = 0; j < 4; j++) {
            float zh = tr ? ms[j] + gum_scr(us[j]) : ms[j];
            uint32_t cls;
            if (zh > zhi_scr) { cls = 1u; gt++; }
            else if (zh < zlo_scr) cls = 0u;
            else {
                float ze = tr ? ms[j] + gum_fast(us[j]) : ms[j];
                uint32_t key = f2k(ze);
                if (key >= hiB) { cls = 1u; gt++; }
                else if (key >= kb) { atomicAdd(&hist2[key - kb], 1u); cls = 2u; }
                else cls = 0u;
            }
            bc0 |= cls << (2 * j);
        }
        map[p0] = (unsigned char)bc0;
    }
    red[threadIdx.x] = gt;
    __syncthreads();
    for (int off = NTHR / 2; off; off >>= 1) {
        if (threadIdx.x < off) red[threadIdx.x] += red[threadIdx.x + off];
        __syncthreads();
    }
    if (threadIdx.x == 0 && red[0]) atomicAdd(&scal[1], red[0]);
}

// ---------- K4: scan hist2 (2^17 bins, strips of 128), window [klo,khi], caw ----------
__global__ void __launch_bounds__(1024) k_scan2(
        const uint32_t* __restrict__ hist2, const int* __restrict__ kptr,
        uint32_t* __restrict__ scal) {
    __shared__ uint32_t ss[1024];     // reversed strip sums -> inclusive scan from top
    __shared__ uint32_t bs[1024];
    __shared__ uint32_t red[1024];
    __shared__ int shI[2];
    const int t = threadIdx.x;
    const uint32_t kb = scal[0];
    if (t < 2) shI[t] = 0;

    // strip (1023 - t): sum its 128 bins
    const int s = 1023 - t;
    uint32_t sum = 0;
    for (int j = 0; j < 128; j++) sum += hist2[(s << 7) + j];
    ss[t] = sum;
    __syncthreads();
    for (int off = 1; off < 1024; off <<= 1) {
        uint32_t add = (t >= off) ? ss[t - off] : 0u;
        __syncthreads();
        ss[t] += add;
        __syncthreads();
    }
    const uint32_t GT = scal[1];
    const uint32_t kk1 = (uint32_t)(*kptr) - GT;   // rank within hist2 range, from top
    {
        uint32_t excl = t ? ss[t - 1] : 0u;
        if (excl < kk1 && kk1 <= ss[t]) shI[0] = t;
    }
    __syncthreads();
    const int rp = shI[0];
    const int sstrip = 1023 - rp;                  // strip containing rank kk1
    const uint32_t gt_strips = rp ? ss[rp - 1] : 0u;
    const uint32_t kk_in = kk1 - gt_strips;

    // scan the 128 bins of that strip (reversed), locate b2
    bs[t] = (t < 128) ? hist2[(sstrip << 7) + (127 - t)] : 0u;
    __syncthreads();
    for (int off = 1; off < 1024; off <<= 1) {
        uint32_t add = (t >= off) ? bs[t - off] : 0u;
        __syncthreads();
        bs[t] += add;
        __syncthreads();
    }
    {
        uint32_t excl = t ? bs[t - 1] : 0u;
        if (t < 128 && excl < kk_in && kk_in <= bs[t]) shI[1] = t;
    }
    __syncthreads();
    const int rq = shI[1];
    const int b2 = (sstrip << 7) + (127 - rq);     // threshold offset within range

    // window +-W ulps, shrink if overpopulated (exact counts)
    int W = 64;
    int lo = 0, hi = 0;
    uint32_t caw = 0;
    while (true) {
        lo = b2 - W; if (lo < 0) lo = 0;
        hi = b2 + W; if (hi > (int)H2SIZE - 1) hi = (int)H2SIZE - 1;
        uint32_t v = 0;
        for (int b = lo + t; b <= hi; b += 1024) v += hist2[b];
        red[t] = v;
        __syncthreads();
        for (int off = 512; off; off >>= 1) {
            if (t < off) red[t] += red[t + off];
            __syncthreads();
        }
        uint32_t nW = red[0];
        __syncthreads();
        if (nW <= 3500u || W == 0) {
            // caw = GT + strips fully above hi's strip + partial of hi's strip above hi
            const int hs = hi >> 7;
            const int hend = ((hs + 1) << 7) - 1;
            uint32_t v2 = 0;
            for (int b = hi + 1 + t; b <= hend; b += 1024) v2 += hist2[b];
            red[t] = v2;
            __syncthreads();
            for (int off = 512; off; off >>= 1) {
                if (t < off) red[t] += red[t + off];
                __syncthreads();
            }
            uint32_t inpart = red[0];
            __syncthreads();
            const int rp_hs = 1023 - hs;
            const uint32_t strips_above = rp_hs ? ss[rp_hs - 1] : 0u;
            caw = GT + strips_above + inpart;
            break;
        }
        W >>= 1;
    }
    if (t == 0) {
        scal[3] = kb + (uint32_t)lo;  // klo
        scal[4] = kb + (uint32_t)hi;  // khi
        scal[5] = caw;
    }
}

// ---------- K5: final pass — map-driven decide, gather exact only for band ----------
// u2 INTERLEAVED: pair for element i is (u2[2i], u2[2i+1]).
__global__ void __launch_bounds__(NTHR) k_final(
        const unsigned char* __restrict__ map,
        const float* __restrict__ lg, const float* __restrict__ u1,
        const float* __restrict__ u2, const int* __restrict__ trainp,
        const uint32_t* __restrict__ scal,
        uint32_t* __restrict__ candIdx, uint32_t* __restrict__ candCount,
        float* __restrict__ out, int N) {
    const uint32_t klo = scal[3], khi = scal[4];
    const int tr = *trainp;
    const int n4 = N >> 2;
    const int tid = blockIdx.x * NTHR + threadIdx.x;
    const int stride = gridDim.x * NTHR;
    const float4* u24 = (const float4*)u2;
    const float4* lg4 = (const float4*)lg;
    const float4* u14 = (const float4*)u1;

    for (int i = tid; i < n4; i += stride) {
        const unsigned int b = map[i];
        float4 ua4, ub4;
        if (tr) { ua4 = u24[2 * i]; ub4 = u24[2 * i + 1]; }
        // deinterleave pairs: element j uses (pa[j], pb[j])
        float pa[4] = {ua4.x, ua4.z, ub4.x, ub4.z};
        float pb[4] = {ua4.y, ua4.w, ub4.y, ub4.w};
        const bool has2 = ((b & 3u) == 2u) | (((b >> 2) & 3u) == 2u) |
                          (((b >> 4) & 3u) == 2u) | (((b >> 6) & 3u) == 2u);
        float me[4], ue[4];
        if (has2) {
            float4 mm = lg4[i];
            float4 uu = u14[i];
            me[0] = mm.x; me[1] = mm.y; me[2] = mm.z; me[3] = mm.w;
            ue[0] = uu.x; ue[1] = uu.y; ue[2] = uu.z; ue[3] = uu.w;
        }
        float res[4];
        bool cand[4];
        bool anyc = false;
        #pragma unroll
        for (int j = 0; j < 4; j++) {
            const unsigned int cls = (b >> (2 * j)) & 3u;
            cand[j] = false;
            if (cls == 0u) {
                res[j] = tr ? decide0(pa[j], pb[j]) : 0.0f;
            } else if (cls == 1u) {
                res[j] = tr ? decide_fast(1.0f, pa[j], pb[j]) : 1.0f;
            } else {
                float ze = tr ? me[j] + gum_fast(ue[j]) : me[j];
                uint32_t key = f2k(ze);
                if (key > khi) res[j] = tr ? decide_fast(1.0f, pa[j], pb[j]) : 1.0f;
                else if (key < klo) res[j] = tr ? decide0(pa[j], pb[j]) : 0.0f;
                else { cand[j] = true; anyc = true; res[j] = 0.0f; }
            }
        }
        if (!anyc) {
            ((float4*)out)[i] = make_float4(res[0], res[1], res[2], res[3]);
        } else {
            #pragma unroll
            for (int j = 0; j < 4; j++) {
                if (cand[j]) {
                    uint32_t p = atomicAdd(candCount, 1u);
                    if (p < CAND_CAP) candIdx[p] = (uint32_t)(4 * i + j);
                } else {
                    out[4 * i + j] = res[j];
                }
            }
        }
    }
}

// ---------- K6: refine window candidates exactly (CR log, bitonic, select) ----------
__global__ void __launch_bounds__(NTHR) k_refine(
        const float* __restrict__ lg, const float* __restrict__ u1,
        const float* __restrict__ u2, const int* __restrict__ kptr,
        const int* __restrict__ trainp, const uint32_t* __restrict__ scal,
        const uint32_t* __restrict__ candIdx, const uint32_t* __restrict__ candCount,
        float* __restrict__ out) {
    __shared__ float zs[CAND_CAP];
    __shared__ int is[CAND_CAP];
    const int tr = *trainp;
    int n = (int)(*candCount);
    if (n > CAND_CAP) n = CAND_CAP;
    int npow2 = 64;
    while (npow2 < n) npow2 <<= 1;

    for (int e = threadIdx.x; e < npow2; e += NTHR) {
        if (e < n) {
            int i = (int)candIdx[e];
            float m = lg[i];
            zs[e] = tr ? (m + gum_cr(u1[i])) : m;
            is[e] = i;
        } else {
            zs[e] = -INFINITY;
            is[e] = 0x40000000 + e;
        }
    }
    __syncthreads();

    // bitonic: descending by z, ascending index on ties (matches lax.top_k)
    for (int size = 2; size <= npow2; size <<= 1) {
        for (int str = size >> 1; str > 0; str >>= 1) {
            for (int e = threadIdx.x; e < npow2; e += NTHR) {
                int p = e ^ str;
                if (p > e) {
                    float za = zs[e], zb = zs[p];
                    int ia = is[e], ib = is[p];
                    bool aBefore = (za > zb) || (za == zb && ia < ib);
                    bool descBlock = ((e & size) == 0);
                    if (descBlock ? !aBefore : aBefore) {
                        zs[e] = zb; zs[p] = za;
                        is[e] = ib; is[p] = ia;
                    }
                }
            }
            __syncthreads();
        }
    }

    const int K = *kptr;
    const int caw = (int)scal[5];
    const int R = K - caw;
    for (int e = threadIdx.x; e < n; e += NTHR) {
        int i = is[e];
        float mv = (e < R) ? 1.0f : 0.0f;
        out[i] = tr ? decide_cr(mv, u2[2 * i], u2[2 * i + 1]) : mv;
    }
}

// ---------- launcher ----------
extern "C" void kernel_launch(void* const* d_in, const int* in_sizes, int n_in,
                              void* d_out, int out_size, void* d_ws, size_t ws_size,
                              hipStream_t stream) {
    const float* lg = (const float*)d_in[0];
    const float* u1 = (const float*)d_in[1];
    const float* u2 = (const float*)d_in[2];
    const int* kptr = (const int*)d_in[3];
    const int* trainp = (const int*)d_in[4];
    float* out = (float*)d_out;
    const int N = in_sizes[0];

    // workspace layout (~5.2 MB)
    uint32_t* hist1r = (uint32_t*)d_ws;              // NREP*4096  (512 KB)
    uint32_t* hist2 = hist1r + NREP * 4096;          // 2^17       (512 KB)
    uint32_t* scal = hist2 + H2SIZE;                 // 16
    uint32_t* candCount = scal + 16;                 // 1
    uint32_t* candIdx = candCount + 1;               // CAND_CAP
    unsigned char* map = (unsigned char*)(candIdx + CAND_CAP);  // N/4 bytes (~4 MB)

    k_zero<<<dim3(256), dim3(NTHR), 0, stream>>>(hist1r, hist2, scal, candCount);
    k_samp<<<dim3(256), dim3(NTHR), 0, stream>>>(lg, u1, trainp, hist1r, N);
    k_scan1<<<dim3(1), dim3(1024), 0, stream>>>(hist1r, kptr, scal);
    k_map<<<dim3(GRID_MAP), dim3(NTHR), 0, stream>>>(lg, u1, trainp, scal, hist2,
                                                     scal, map, N);
    k_scan2<<<dim3(1), dim3(1024), 0, stream>>>(hist2, kptr, scal);
    k_final<<<dim3(GRID_FIN), dim3(NTHR), 0, stream>>>(map, lg, u1, u2, trainp, scal,
                                                       candIdx, candCount, out, N);
    k_refine<<<dim3(1), dim3(NTHR), 0, stream>>>(lg, u1, u2, kptr, trainp, scal,
                                                 candIdx, candCount, out);
}

// Round 11
// 196.357 us; speedup vs baseline: 1.0259x; 1.0259x over previous
//
#include <hip/hip_runtime.h>
#include <hip/hip_bf16.h>
#include <math.h>
#include <cstdint>

#define FEPS 1e-8f
#define NTHR 256
#define CAND_CAP 4096
#define NREP 32
#define H2BITS 17
#define H2SIZE (1u << H2BITS)

#define GRID_KEYS 2048
#define GRID_FIN  2048

// coarse sampled binning: 4096 bins over [-8, 24), width 1/128
#define ZMIN 8.0f
#define ZSCALE 128.0f
#define ZBINW 0.0078125f    // exact in f32

// ---------- numeric helpers ----------

// monotonic float <-> uint key mapping (order-preserving, ascending)
__device__ __forceinline__ uint32_t f2k(float f) {
    uint32_t b = __float_as_uint(f);
    return (b & 0x80000000u) ? ~b : (b | 0x80000000u);
}

// exact-path gumbel: library logf (~1 ulp) — the "truth" z for all counts
__device__ __forceinline__ float gum_fast(float u) {
    float t = u + FEPS;
    float a = logf(t);
    float w = -a + FEPS;
    return -logf(w);
}
// screen-path gumbel (sampling only): fast __logf
__device__ __forceinline__ float gum_scr(float u) {
    float t = u + FEPS;
    float a = __logf(t);
    float w = -a + FEPS;
    return -__logf(w);
}

// refine/tie path: f64 log (empirically matches np reference)
__device__ __forceinline__ float logCR(float x) { return (float)log((double)x); }
__device__ __forceinline__ float gum_cr(float u) {
    float t = u + FEPS;
    float a = logCR(t);
    float w = -a + FEPS;
    return -logCR(w);
}

// exact decision: out = 1 iff RN(v1 - v0) > 2^-25
__device__ __forceinline__ float decide_cr(float maskv, float ua, float ub) {
    float G0 = gum_cr(ua);
    float G1 = gum_cr(ub);
    float diff = (maskv + G1) - G0;
    return (diff > 0x1p-25f) ? 1.0f : 0.0f;
}

// ratio trick (R9-proven): out=1 iff w0 > exp(2^-25-mv)*w1; CR fallback in 1e-4 band
__device__ __forceinline__ float decide_fast(float mv, float ua, float ub) {
    float w0 = -logf(ua + FEPS) + FEPS;
    float w1 = -logf(ub + FEPS) + FEPS;
    float T = (mv != 0.0f) ? 0.36787944f : 1.0f;
    float rhs = T * w1;
    float q = w0 - rhs;
    if (fabsf(q) > 1e-4f * rhs) return (q > 0.0f) ? 1.0f : 0.0f;
    return decide_cr(mv, ua, ub);
}

__device__ __forceinline__ int zbin(float z) {
    float t = (z + ZMIN) * ZSCALE;
    int b = (int)t;
    if (b < 0) b = 0;
    if (b > 4095) b = 4095;
    return b;
}

// ---------- K0: zero workspace (~1 MB) ----------
__global__ void k_zero(uint32_t* __restrict__ hist1r, uint32_t* __restrict__ hist2,
                       uint32_t* __restrict__ scal, uint32_t* __restrict__ candCount) {
    int i = blockIdx.x * blockDim.x + threadIdx.x;
    int stride = gridDim.x * blockDim.x;
    for (int b = i; b < NREP * 4096; b += stride) hist1r[b] = 0u;
    for (uint32_t b = i; b < H2SIZE; b += stride) hist2[b] = 0u;
    if (i < 16) scal[i] = 0u;
    if (i == 0) *candCount = 0u;
}

// ---------- K1: SAMPLED coarse histogram (1/16 of elements, screen-z) [R10-proven] ----------
__global__ void __launch_bounds__(NTHR) k_samp(
        const float* __restrict__ lg, const float* __restrict__ u1,
        const int* __restrict__ trainp, uint32_t* __restrict__ hist1r, int N) {
    __shared__ uint32_t h[4096];
    for (int b = threadIdx.x; b < 4096; b += NTHR) h[b] = 0u;
    __syncthreads();
    const int tr = *trainp;
    const int n4 = N >> 2;
    const int gtid = blockIdx.x * NTHR + threadIdx.x;    // 0..65535
    const float4* lg4 = (const float4*)lg;
    const float4* u14 = (const float4*)u1;
    #pragma unroll
    for (int q = 0; q < 4; q++) {
        int pos = (gtid + q * 65536) << 4;   // every 16th float4-position
        if (pos < n4) {
            float4 m = lg4[pos];
            float4 u = u14[pos];
            float z0 = tr ? m.x + gum_scr(u.x) : m.x;
            float z1 = tr ? m.y + gum_scr(u.y) : m.y;
            float z2 = tr ? m.z + gum_scr(u.z) : m.z;
            float z3 = tr ? m.w + gum_scr(u.w) : m.w;
            atomicAdd(&h[zbin(z0)], 1u); atomicAdd(&h[zbin(z1)], 1u);
            atomicAdd(&h[zbin(z2)], 1u); atomicAdd(&h[zbin(z3)], 1u);
        }
    }
    __syncthreads();
    uint32_t* rep = hist1r + (uint32_t)(blockIdx.x & (NREP - 1)) * 4096u;
    for (int b = threadIdx.x; b < 4096; b += NTHR) {
        uint32_t v = h[b];
        if (v) atomicAdd(&rep[b], v);
    }
}

// ---------- K2: scan sampled hist -> keybase (with -2 bin margin) [R10-proven] ----------
__global__ void __launch_bounds__(1024) k_scan1(
        const uint32_t* __restrict__ hist1r, const int* __restrict__ kptr,
        uint32_t* __restrict__ scal) {
    __shared__ uint32_t vals[4096];
    __shared__ uint32_t cnt[1024];
    const int t = threadIdx.x;
    uint32_t loc = 0;
    for (int j = 0; j < 4; j++) {
        const int bin = 4095 - (t * 4 + j);
        uint32_t v = 0;
        #pragma unroll
        for (int r = 0; r < NREP; r++) v += hist1r[r * 4096 + bin];
        vals[t * 4 + j] = v;
        loc += v;
    }
    cnt[t] = loc;
    __syncthreads();
    for (int off = 1; off < 1024; off <<= 1) {
        uint32_t add = (t >= off) ? cnt[t - off] : 0u;
        __syncthreads();
        cnt[t] += add;
        __syncthreads();
    }
    const float Kf = (float)(*kptr) * 0.0625f;   // target rank among 1/16 samples
    float excl = (t > 0) ? (float)cnt[t - 1] : 0.0f;
    float incl = (float)cnt[t];
    if (excl < Kf && Kf <= incl) {
        float c = excl;
        for (int j = 0; j < 4; j++) {
            float v = (float)vals[t * 4 + j];
            if (Kf <= c + v) {
                int b1 = 4095 - (t * 4 + j);          // estimated threshold bin
                int bmar = b1 - 2;                    // sampling-noise margin
                if (bmar < 0) bmar = 0;
                float elo = (float)bmar * ZBINW - ZMIN;  // exact dyadic edge
                scal[0] = f2k(elo);                   // keybase
                break;
            }
            c += v;
        }
    }
}

// ---------- K3: pure stream — exact keys + fused 1-ulp hist2 + exact GT ----------
// NO LDS histogram (the ablation). kb known beforehand from sampled scan1.
__global__ void __launch_bounds__(NTHR) k_keys(
        const float* __restrict__ lg, const float* __restrict__ u1,
        const int* __restrict__ trainp, const uint32_t* __restrict__ scal_ro,
        uint32_t* __restrict__ keys, uint32_t* __restrict__ hist2,
        uint32_t* __restrict__ scal, int N) {
    __shared__ uint32_t red[NTHR];
    const int tr = *trainp;
    const uint32_t kb = scal_ro[0];
    const uint32_t hiB = kb + H2SIZE;
    const int n4 = N >> 2;
    const int nth = gridDim.x * NTHR;
    const float4* lg4 = (const float4*)lg;
    const float4* u14 = (const float4*)u1;
    uint4* k4 = (uint4*)keys;
    uint32_t gt = 0;

    int p0 = blockIdx.x * NTHR + threadIdx.x;
    while (p0 + nth < n4) {
        const int p1 = p0 + nth;
        float4 m0 = lg4[p0];
        float4 m1 = lg4[p1];
        float4 a0 = u14[p0];
        float4 a1 = u14[p1];
        float z0, z1, z2, z3, z4, z5, z6, z7;
        if (tr) {
            z0 = m0.x + gum_fast(a0.x); z1 = m0.y + gum_fast(a0.y);
            z2 = m0.z + gum_fast(a0.z); z3 = m0.w + gum_fast(a0.w);
            z4 = m1.x + gum_fast(a1.x); z5 = m1.y + gum_fast(a1.y);
            z6 = m1.z + gum_fast(a1.z); z7 = m1.w + gum_fast(a1.w);
        } else {
            z0 = m0.x; z1 = m0.y; z2 = m0.z; z3 = m0.w;
            z4 = m1.x; z5 = m1.y; z6 = m1.z; z7 = m1.w;
        }
        uint32_t ks[8] = {f2k(z0), f2k(z1), f2k(z2), f2k(z3),
                          f2k(z4), f2k(z5), f2k(z6), f2k(z7)};
        k4[p0] = make_uint4(ks[0], ks[1], ks[2], ks[3]);
        k4[p1] = make_uint4(ks[4], ks[5], ks[6], ks[7]);
        #pragma unroll
        for (int j = 0; j < 8; j++) {
            uint32_t kx = ks[j];
            if (kx >= hiB) gt++;
            else if (kx >= kb) atomicAdd(&hist2[kx - kb], 1u);
        }
        p0 += 2 * nth;
    }
    if (p0 < n4) {
        float4 m0 = lg4[p0];
        float4 a0 = u14[p0];
        float z0, z1, z2, z3;
        if (tr) {
            z0 = m0.x + gum_fast(a0.x); z1 = m0.y + gum_fast(a0.y);
            z2 = m0.z + gum_fast(a0.z); z3 = m0.w + gum_fast(a0.w);
        } else { z0 = m0.x; z1 = m0.y; z2 = m0.z; z3 = m0.w; }
        uint32_t ks[4] = {f2k(z0), f2k(z1), f2k(z2), f2k(z3)};
        k4[p0] = make_uint4(ks[0], ks[1], ks[2], ks[3]);
        #pragma unroll
        for (int j = 0; j < 4; j++) {
            uint32_t kx = ks[j];
            if (kx >= hiB) gt++;
            else if (kx >= kb) atomicAdd(&hist2[kx - kb], 1u);
        }
    }
    for (int i = (n4 << 2) + blockIdx.x * NTHR + threadIdx.x; i < N; i += nth) {
        float m = lg[i], u = u1[i];
        float z = tr ? (m + gum_fast(u)) : m;
        uint32_t kx = f2k(z);
        keys[i] = kx;
        if (kx >= hiB) gt++;
        else if (kx >= kb) atomicAdd(&hist2[kx - kb], 1u);
    }
    red[threadIdx.x] = gt;
    __syncthreads();
    for (int off = NTHR / 2; off; off >>= 1) {
        if (threadIdx.x < off) red[threadIdx.x] += red[threadIdx.x + off];
        __syncthreads();
    }
    if (threadIdx.x == 0 && red[0]) atomicAdd(&scal[1], red[0]);
}

// ---------- K4: scan hist2 (2^17 bins, strips of 128), window [klo,khi], caw [R10-proven] ----------
__global__ void __launch_bounds__(1024) k_scan2(
        const uint32_t* __restrict__ hist2, const int* __restrict__ kptr,
        uint32_t* __restrict__ scal) {
    __shared__ uint32_t ss[1024];
    __shared__ uint32_t bs[1024];
    __shared__ uint32_t red[1024];
    __shared__ int shI[2];
    const int t = threadIdx.x;
    const uint32_t kb = scal[0];
    if (t < 2) shI[t] = 0;

    const int s = 1023 - t;
    uint32_t sum = 0;
    for (int j = 0; j < 128; j++) sum += hist2[(s << 7) + j];
    ss[t] = sum;
    __syncthreads();
    for (int off = 1; off < 1024; off <<= 1) {
        uint32_t add = (t >= off) ? ss[t - off] : 0u;
        __syncthreads();
        ss[t] += add;
        __syncthreads();
    }
    const uint32_t GT = scal[1];
    const uint32_t kk1 = (uint32_t)(*kptr) - GT;
    {
        uint32_t excl = t ? ss[t - 1] : 0u;
        if (excl < kk1 && kk1 <= ss[t]) shI[0] = t;
    }
    __syncthreads();
    const int rp = shI[0];
    const int sstrip = 1023 - rp;
    const uint32_t gt_strips = rp ? ss[rp - 1] : 0u;
    const uint32_t kk_in = kk1 - gt_strips;

    bs[t] = (t < 128) ? hist2[(sstrip << 7) + (127 - t)] : 0u;
    __syncthreads();
    for (int off = 1; off < 1024; off <<= 1) {
        uint32_t add = (t >= off) ? bs[t - off] : 0u;
        __syncthreads();
        bs[t] += add;
        __syncthreads();
    }
    {
        uint32_t excl = t ? bs[t - 1] : 0u;
        if (t < 128 && excl < kk_in && kk_in <= bs[t]) shI[1] = t;
    }
    __syncthreads();
    const int rq = shI[1];
    const int b2 = (sstrip << 7) + (127 - rq);

    int W = 64;
    int lo = 0, hi = 0;
    uint32_t caw = 0;
    while (true) {
        lo = b2 - W; if (lo < 0) lo = 0;
        hi = b2 + W; if (hi > (int)H2SIZE - 1) hi = (int)H2SIZE - 1;
        uint32_t v = 0;
        for (int b = lo + t; b <= hi; b += 1024) v += hist2[b];
        red[t] = v;
        __syncthreads();
        for (int off = 512; off; off >>= 1) {
            if (t < off) red[t] += red[t + off];
            __syncthreads();
        }
        uint32_t nW = red[0];
        __syncthreads();
        if (nW <= 3500u || W == 0) {
            const int hs = hi >> 7;
            const int hend = ((hs + 1) << 7) - 1;
            uint32_t v2 = 0;
            for (int b = hi + 1 + t; b <= hend; b += 1024) v2 += hist2[b];
            red[t] = v2;
            __syncthreads();
            for (int off = 512; off; off >>= 1) {
                if (t < off) red[t] += red[t + off];
                __syncthreads();
            }
            uint32_t inpart = red[0];
            __syncthreads();
            const int rp_hs = 1023 - hs;
            const uint32_t strips_above = rp_hs ? ss[rp_hs - 1] : 0u;
            caw = GT + strips_above + inpart;
            break;
        }
        W >>= 1;
    }
    if (t == 0) {
        scal[3] = kb + (uint32_t)lo;  // klo
        scal[4] = kb + (uint32_t)hi;  // khi
        scal[5] = caw;
    }
}

// ---------- K5: final pass (R9-proven shape) ----------
// u2 INTERLEAVED: pair for element i is (u2[2i], u2[2i+1]); per uint4-position,
// uu[] = {a0,b0,a1,b1,a2,b2,a3,b3}; element j uses (uu[2j], uu[2j+1]).
__global__ void __launch_bounds__(NTHR) k_final(
        uint32_t* __restrict__ keys /* == (uint32_t*)d_out */,
        const float* __restrict__ u2, const int* __restrict__ trainp,
        const uint32_t* __restrict__ scal,
        uint32_t* __restrict__ candIdx, uint32_t* __restrict__ candCount, int N) {
    const uint32_t klo = scal[3], khi = scal[4];
    const int tr = *trainp;
    const int n4 = N >> 2;
    const int tid = blockIdx.x * NTHR + threadIdx.x;
    const int stride = gridDim.x * NTHR;
    const uint4* kr4 = (const uint4*)keys;
    const float4* u24 = (const float4*)u2;
    float* outf = (float*)keys;

    for (int i = tid; i < n4; i += stride) {
        uint4 kk = kr4[i];
        uint32_t ks[4] = {kk.x, kk.y, kk.z, kk.w};
        float uu[8];
        if (tr) {
            float4 ua = u24[2 * i];
            float4 ub = u24[2 * i + 1];
            uu[0] = ua.x; uu[1] = ua.y; uu[2] = ua.z; uu[3] = ua.w;
            uu[4] = ub.x; uu[5] = ub.y; uu[6] = ub.z; uu[7] = ub.w;
        }
        float res[4];
        bool inw[4];
        bool anyw = false;
        #pragma unroll
        for (int j = 0; j < 4; j++) {
            inw[j] = (ks[j] >= klo) && (ks[j] <= khi);
            anyw |= inw[j];
        }
        #pragma unroll
        for (int j = 0; j < 4; j++) {
            float mv = (ks[j] > khi) ? 1.0f : 0.0f;
            res[j] = (tr && !inw[j]) ? decide_fast(mv, uu[2 * j], uu[2 * j + 1]) : mv;
        }
        if (!anyw) {
            ((float4*)outf)[i] = make_float4(res[0], res[1], res[2], res[3]);
        } else {
            #pragma unroll
            for (int j = 0; j < 4; j++) {
                if (inw[j]) {
                    uint32_t p = atomicAdd(candCount, 1u);
                    if (p < CAND_CAP) candIdx[p] = (uint32_t)(4 * i + j);
                } else {
                    outf[4 * i + j] = res[j];
                }
            }
        }
    }
    for (int i = (n4 << 2) + tid; i < N; i += stride) {  // tail
        uint32_t kx = keys[i];
        if (kx >= klo && kx <= khi) {
            uint32_t p = atomicAdd(candCount, 1u);
            if (p < CAND_CAP) candIdx[p] = (uint32_t)i;
            continue;
        }
        float mv = (kx > khi) ? 1.0f : 0.0f;
        outf[i] = tr ? decide_fast(mv, u2[2 * i], u2[2 * i + 1]) : mv;
    }
}

// ---------- K6: refine window candidates exactly (CR log, bitonic, select) ----------
__global__ void __launch_bounds__(NTHR) k_refine(
        const float* __restrict__ lg, const float* __restrict__ u1,
        const float* __restrict__ u2, const int* __restrict__ kptr,
        const int* __restrict__ trainp, const uint32_t* __restrict__ scal,
        const uint32_t* __restrict__ candIdx, const uint32_t* __restrict__ candCount,
        float* __restrict__ out) {
    __shared__ float zs[CAND_CAP];
    __shared__ int is[CAND_CAP];
    const int tr = *trainp;
    int n = (int)(*candCount);
    if (n > CAND_CAP) n = CAND_CAP;
    int npow2 = 64;
    while (npow2 < n) npow2 <<= 1;

    for (int e = threadIdx.x; e < npow2; e += NTHR) {
        if (e < n) {
            int i = (int)candIdx[e];
            float m = lg[i];
            zs[e] = tr ? (m + gum_cr(u1[i])) : m;
            is[e] = i;
        } else {
            zs[e] = -INFINITY;
            is[e] = 0x40000000 + e;
        }
    }
    __syncthreads();

    // bitonic: descending by z, ascending index on ties (matches lax.top_k)
    for (int size = 2; size <= npow2; size <<= 1) {
        for (int str = size >> 1; str > 0; str >>= 1) {
            for (int e = threadIdx.x; e < npow2; e += NTHR) {
                int p = e ^ str;
                if (p > e) {
                    float za = zs[e], zb = zs[p];
                    int ia = is[e], ib = is[p];
                    bool aBefore = (za > zb) || (za == zb && ia < ib);
                    bool descBlock = ((e & size) == 0);
                    if (descBlock ? !aBefore : aBefore) {
                        zs[e] = zb; zs[p] = za;
                        is[e] = ib; is[p] = ia;
                    }
                }
            }
            __syncthreads();
        }
    }

    const int K = *kptr;
    const int caw = (int)scal[5];
    const int R = K - caw;
    for (int e = threadIdx.x; e < n; e += NTHR) {
        int i = is[e];
        float mv = (e < R) ? 1.0f : 0.0f;
        out[i] = tr ? decide_cr(mv, u2[2 * i], u2[2 * i + 1]) : mv;
    }
}

// ---------- launcher ----------
extern "C" void kernel_launch(void* const* d_in, const int* in_sizes, int n_in,
                              void* d_out, int out_size, void* d_ws, size_t ws_size,
                              hipStream_t stream) {
    const float* lg = (const float*)d_in[0];
    const float* u1 = (const float*)d_in[1];
    const float* u2 = (const float*)d_in[2];
    const int* kptr = (const int*)d_in[3];
    const int* trainp = (const int*)d_in[4];
    float* out = (float*)d_out;
    const int N = in_sizes[0];

    uint32_t* keys = (uint32_t*)d_out;   // staged in d_out, overwritten by results

    // workspace (~1.1 MB)
    uint32_t* hist1r = (uint32_t*)d_ws;              // NREP*4096  (512 KB)
    uint32_t* hist2 = hist1r + NREP * 4096;          // 2^17       (512 KB)
    uint32_t* scal = hist2 + H2SIZE;                 // 16
    uint32_t* candCount = scal + 16;                 // 1
    uint32_t* candIdx = candCount + 1;               // CAND_CAP

    k_zero<<<dim3(256), dim3(NTHR), 0, stream>>>(hist1r, hist2, scal, candCount);
    k_samp<<<dim3(256), dim3(NTHR), 0, stream>>>(lg, u1, trainp, hist1r, N);
    k_scan1<<<dim3(1), dim3(1024), 0, stream>>>(hist1r, kptr, scal);
    k_keys<<<dim3(GRID_KEYS), dim3(NTHR), 0, stream>>>(lg, u1, trainp, scal, keys,
                                                       hist2, scal, N);
    k_scan2<<<dim3(1), dim3(1024), 0, stream>>>(hist2, kptr, scal);
    k_final<<<dim3(GRID_FIN), dim3(NTHR), 0, stream>>>(keys, u2, trainp, scal,
                                                       candIdx, candCount, N);
    k_refine<<<dim3(1), dim3(NTHR), 0, stream>>>(lg, u1, u2, kptr, trainp, scal,
                                                 candIdx, candCount, out);
}